// Round 3
// baseline (77.043 us; speedup 1.0000x reference)
//
#include <hip/hip_runtime.h>
#include <math.h>

#define B_ 2048
#define D_ 512
#define H_ 512
#define A_ 18
#define T_ 16
#define MT 16
#define MAXTILES 144
#define RT 32          // rows per fused block
#define NTILE 8        // row-tiles per task capacity (8*32=256 rows/task)

typedef __attribute__((ext_vector_type(8))) short short8;
typedef __attribute__((ext_vector_type(4))) float f32x4;

#define WS_NEED (8 * 1024 * 1024)   // w1t bf16 [T][H][D] at ws offset 0

__device__ __forceinline__ unsigned short f2bf(float f) {
    union { float f; unsigned int u; } v; v.f = f;
    unsigned int u = v.u;
    return (unsigned short)((u + 0x7fffu + ((u >> 16) & 1u)) >> 16);
}
__device__ __forceinline__ float bf2f(unsigned short h) {
    union { unsigned int u; float f; } v; v.u = ((unsigned int)h) << 16;
    return v.f;
}

// ---- W1 [T][D][H] fp32  ->  w1t [T][H][D] bf16 (proven in round 2) ----
__global__ __launch_bounds__(256) void nk_w1t(const float* __restrict__ W1,
                                              unsigned short* __restrict__ w1t) {
    __shared__ float tile[64][65];
    int t = blockIdx.z, d0 = blockIdx.y * 64, h0 = blockIdx.x * 64;
    int tid = threadIdx.x, cx = tid & 63, ry = tid >> 6;
    const float* src = W1 + ((size_t)t * D_ + d0) * H_ + h0;
#pragma unroll
    for (int i = 0; i < 16; ++i) {
        int row = i * 4 + ry;
        tile[row][cx] = src[(size_t)row * H_ + cx];
    }
    __syncthreads();
    unsigned short* dst = w1t + ((size_t)t * H_ + h0) * D_ + d0;
#pragma unroll
    for (int i = 0; i < 16; ++i) {
        int hr = i * 4 + ry;
        dst[(size_t)hr * D_ + cx] = f2bf(tile[cx][hr]);
    }
}

// ---- fully fused: ballot-sort + fc1 MFMA + relu + fc2 + softmax ----
__global__ __launch_bounds__(512) void nk_fused(
        const float* __restrict__ xs, const unsigned short* __restrict__ w1t,
        const float* __restrict__ b1, const float* __restrict__ W2,
        const float* __restrict__ b2, const int* __restrict__ task_id,
        const int* __restrict__ action, float* __restrict__ out) {
    __shared__ float h_lds[RT][H_ + 4];   // 32 x 516 fp32 = 66 KB
    __shared__ int sidx[RT];

    int t = blockIdx.x;          // task
    int kt = blockIdx.y;         // row-tile within task
    int base = kt * RT;
    int tid = threadIdx.x;
    int lane = tid & 63;
    int w = tid >> 6;            // wave 0..7

    if (tid < RT) sidx[tid] = 0;
    __syncthreads();

    // ballot-scan over task_id: find sorted rows [base, base+RT) for task t.
    // All 8 waves compute redundantly (identical results; benign same-value writes).
    unsigned long long ltm = (1ull << lane) - 1ull;
    int run = 0;
    for (int i = 0; i < B_ / 64; ++i) {
        int b = i * 64 + lane;
        bool m = (task_id[b] == t);
        unsigned long long bal = __ballot(m);
        if (m) {
            int pos = run + __popcll(bal & ltm);
            if (pos >= base && pos < base + RT) sidx[pos - base] = b;
        }
        run += __popcll(bal);
    }
    int rows = run - base;       // may be <=0 (idle tile) or >RT (clamp)
    if (rows <= 0) return;
    if (rows > RT) rows = RT;
    __syncthreads();

    int r15 = lane & 15, kg = lane >> 4;
    int mt = w >> 2;             // m-tile 0/1 (rows mt*16 .. mt*16+15)
    int cq = w & 3;              // col quarter (128 cols)

    // A fragments: 16 K-steps, row = sidx[mt*16 + r15], convert fp32->bf16 in-reg
    int arow = sidx[mt * 16 + r15];
    const float* ap = xs + (size_t)arow * D_ + kg * 8;
    short8 areg[16];
#pragma unroll
    for (int ks = 0; ks < 16; ++ks) {
        float4 x0 = *(const float4*)(ap + ks * 32);
        float4 x1 = *(const float4*)(ap + ks * 32 + 4);
        unsigned short u[8] = { f2bf(x0.x), f2bf(x0.y), f2bf(x0.z), f2bf(x0.w),
                                f2bf(x1.x), f2bf(x1.y), f2bf(x1.z), f2bf(x1.w) };
        areg[ks] = *(const short8*)u;
    }

    // B fragments from w1t[t][n][k] (bf16, K-contiguous); 8 n-tiles per wave
    const unsigned short* bp = w1t + (size_t)t * H_ * D_;
    f32x4 acc[8];
#pragma unroll
    for (int nt = 0; nt < 8; ++nt) acc[nt] = (f32x4){0.f, 0.f, 0.f, 0.f};

    for (int ks = 0; ks < 16; ++ks) {
#pragma unroll
        for (int nt = 0; nt < 8; ++nt) {
            int n = cq * 128 + nt * 16 + r15;
            short8 bfrag = *(const short8*)(bp + (size_t)n * D_ + ks * 32 + kg * 8);
            acc[nt] = __builtin_amdgcn_mfma_f32_16x16x32_bf16(areg[ks], bfrag, acc[nt], 0, 0, 0);
        }
    }

    // bias + relu -> h_lds (fp32)
    const float* b1p = b1 + t * H_;
#pragma unroll
    for (int nt = 0; nt < 8; ++nt) {
        int c = cq * 128 + nt * 16 + r15;
        float bv = b1p[c];
#pragma unroll
        for (int j = 0; j < 4; ++j) {
            int rr = mt * 16 + kg * 4 + j;      // C row = (lane>>4)*4 + reg
            float v = acc[nt][j] + bv;
            h_lds[rr][c] = v > 0.f ? v : 0.f;
        }
    }
    __syncthreads();

    // fc2 + softmax: 16 lanes per row, 32 rows; lane reads float4 h chunks
    int g = tid >> 4, l16 = tid & 15;
    float lg[A_];
#pragma unroll
    for (int a = 0; a < A_; ++a) lg[a] = 0.f;
    const float* w2p = W2 + (size_t)t * H_ * A_;
    if (g < rows) {
#pragma unroll 2
        for (int jj = 0; jj < 8; ++jj) {
            int hh = jj * 64 + l16 * 4;
            float4 hv = *(const float4*)&h_lds[g][hh];
            const float* wr = w2p + (size_t)hh * A_;
#pragma unroll
            for (int a = 0; a < A_; ++a) {
                float s = fmaf(hv.x, wr[a], lg[a]);
                s = fmaf(hv.y, wr[A_ + a], s);
                s = fmaf(hv.z, wr[2 * A_ + a], s);
                lg[a] = fmaf(hv.w, wr[3 * A_ + a], s);
            }
        }
    }
#pragma unroll
    for (int a = 0; a < A_; ++a) {
        lg[a] += __shfl_down(lg[a], 8, 16);
        lg[a] += __shfl_down(lg[a], 4, 16);
        lg[a] += __shfl_down(lg[a], 2, 16);
        lg[a] += __shfl_down(lg[a], 1, 16);
    }
    if (l16 == 0 && g < rows) {
        int b = sidx[g];
        float logits[A_];
        float m = -1e30f;
#pragma unroll
        for (int a = 0; a < A_; ++a) {
            logits[a] = lg[a] + b2[t * A_ + a];
            m = fmaxf(m, logits[a]);
        }
        float S = 0.f, sle = 0.f;
#pragma unroll
        for (int a = 0; a < A_; ++a) {
            float e = expf(logits[a] - m);
            S += e;
            sle += logits[a] * e;
        }
        float logZ = m + logf(S);
        int as = action[b];
        out[b] = (float)as;
        out[B_ + b] = logits[as] - logZ;
        out[2 * B_ + b] = logZ - sle / S;
    }
}

// ---------------- fallback path (round-1, known-good) ----------------

__global__ void nk_init(int* wsi) { int i = threadIdx.x; if (i < 50) wsi[i] = 0; }

__global__ void nk_count(const int* task_id, int* wsi) {
    int b = blockIdx.x * blockDim.x + threadIdx.x;
    if (b < B_) atomicAdd(&wsi[1 + task_id[b]], 1);
}

__global__ void nk_plan(int* wsi) {
    int off = 0, tot = 0;
    for (int t = 0; t < T_; ++t) {
        wsi[17 + t] = off;
        int cnt = wsi[1 + t];
        int nt = (cnt + MT - 1) / MT;
        for (int k = 0; k < nt; ++k) wsi[50 + tot++] = (t << 16) | k;
        off += cnt;
    }
    wsi[17 + T_] = off;
    wsi[0] = tot;
}

__global__ void nk_scatter(const int* task_id, int* wsi) {
    int b = blockIdx.x * blockDim.x + threadIdx.x;
    if (b < B_) {
        int t = task_id[b];
        int pos = atomicAdd(&wsi[34 + t], 1);
        wsi[256 + wsi[17 + t] + pos] = b;
    }
}

__global__ __launch_bounds__(512) void nk_main(
        const float* __restrict__ xs, const float* __restrict__ W1,
        const float* __restrict__ b1, const float* __restrict__ W2,
        const float* __restrict__ b2, const int* __restrict__ task_id,
        const int* __restrict__ action, float* __restrict__ out,
        const int* __restrict__ wsi) {
    __shared__ float tile[MT][D_];
    __shared__ int sidx[MT];
    int bid = blockIdx.x;
    if (bid >= wsi[0]) return;
    int code = wsi[50 + bid];
    int t = code >> 16, kt = code & 0xffff;
    int off0 = wsi[17 + t], off1 = wsi[17 + t + 1];
    int base = off0 + kt * MT;
    int rows = off1 - base; if (rows > MT) rows = MT;
    int tid = threadIdx.x;
    if (tid < MT) sidx[tid] = (tid < rows) ? wsi[256 + base + tid] : -1;
    __syncthreads();
    for (int i = 0; i < MT; ++i) {
        int b = sidx[i];
        tile[i][tid] = (b >= 0) ? xs[(size_t)b * D_ + tid] : 0.f;
    }
    __syncthreads();
    const float* w1p = W1 + (size_t)t * D_ * H_ + tid;
    float acc[MT];
#pragma unroll
    for (int i = 0; i < MT; ++i) acc[i] = 0.f;
    for (int d = 0; d < D_; d += 4) {
        float w0 = w1p[(size_t)(d + 0) * H_];
        float w1v = w1p[(size_t)(d + 1) * H_];
        float w2v = w1p[(size_t)(d + 2) * H_];
        float w3v = w1p[(size_t)(d + 3) * H_];
#pragma unroll
        for (int i = 0; i < MT; ++i) {
            float4 x = *(const float4*)&tile[i][d];
            float a0 = fmaf(x.x, w0, acc[i]);
            a0 = fmaf(x.y, w1v, a0);
            a0 = fmaf(x.z, w2v, a0);
            acc[i] = fmaf(x.w, w3v, a0);
        }
    }
    __syncthreads();
    float b1v = b1[t * H_ + tid];
#pragma unroll
    for (int i = 0; i < MT; ++i) {
        float h = acc[i] + b1v;
        tile[i][tid] = h > 0.f ? h : 0.f;
    }
    __syncthreads();
    int g = tid >> 5, l = tid & 31;
    float lg[A_];
#pragma unroll
    for (int a = 0; a < A_; ++a) lg[a] = 0.f;
    const float* w2base = W2 + (size_t)t * H_ * A_;
    for (int hh = l; hh < H_; hh += 32) {
        float hv = tile[g][hh];
        const float* wrow = w2base + (size_t)hh * A_;
#pragma unroll
        for (int a = 0; a < A_; ++a) lg[a] = fmaf(hv, wrow[a], lg[a]);
    }
#pragma unroll
    for (int a = 0; a < A_; ++a) {
        lg[a] += __shfl_down(lg[a], 16, 32);
        lg[a] += __shfl_down(lg[a], 8, 32);
        lg[a] += __shfl_down(lg[a], 4, 32);
        lg[a] += __shfl_down(lg[a], 2, 32);
        lg[a] += __shfl_down(lg[a], 1, 32);
    }
    if (l == 0 && g < rows) {
        int b = sidx[g];
        float logits[A_];
        float m = -1e30f;
#pragma unroll
        for (int a = 0; a < A_; ++a) {
            logits[a] = lg[a] + b2[t * A_ + a];
            m = fmaxf(m, logits[a]);
        }
        float S = 0.f, sle = 0.f;
#pragma unroll
        for (int a = 0; a < A_; ++a) {
            float e = expf(logits[a] - m);
            S += e;
            sle += logits[a] * e;
        }
        float logZ = m + logf(S);
        int as = action[b];
        out[b] = (float)as;
        out[B_ + b] = logits[as] - logZ;
        out[2 * B_ + b] = logZ - sle / S;
    }
}

extern "C" void kernel_launch(void* const* d_in, const int* in_sizes, int n_in,
                              void* d_out, int out_size, void* d_ws, size_t ws_size,
                              hipStream_t stream) {
    const float* xs = (const float*)d_in[0];
    const float* W1 = (const float*)d_in[1];
    const float* b1 = (const float*)d_in[2];
    const float* W2 = (const float*)d_in[3];
    const float* b2 = (const float*)d_in[4];
    const int* task_id = (const int*)d_in[5];
    const int* action = (const int*)d_in[6];
    float* out = (float*)d_out;

    if (ws_size >= WS_NEED) {
        unsigned short* w1t = (unsigned short*)d_ws;
        nk_w1t<<<dim3(8, 8, T_), 256, 0, stream>>>(W1, w1t);
        nk_fused<<<dim3(T_, NTILE), 512, 0, stream>>>(xs, w1t, b1, W2, b2,
                                                      task_id, action, out);
    } else {
        int* wsi = (int*)d_ws;
        nk_init<<<1, 64, 0, stream>>>(wsi);
        nk_count<<<(B_ + 255) / 256, 256, 0, stream>>>(task_id, wsi);
        nk_plan<<<1, 1, 0, stream>>>(wsi);
        nk_scatter<<<(B_ + 255) / 256, 256, 0, stream>>>(task_id, wsi);
        nk_main<<<MAXTILES, 512, 0, stream>>>(xs, W1, b1, W2, b2, task_id, action, out, wsi);
    }
}

// Round 4
// 50.848 us; speedup vs baseline: 1.5152x; 1.5152x over previous
//
#include <hip/hip_runtime.h>
#include <math.h>

#define B_ 2048
#define D_ 512
#define H_ 512
#define A_ 18
#define T_ 16
#define MT 16
#define MAXTILES 144

typedef __attribute__((ext_vector_type(8))) short short8;
typedef __attribute__((ext_vector_type(4))) float f32x4;

// ws layout:
//   [0..16384)        ints: [0] ntiles | [17..34) offsets[T+1] | [50..194) tiles | [256..2304) order[B]
//   PART_OFF          float part[4][B][A]  (576 KB)
//   W1T_OFF           bf16 w1t[T][H][D]    (8 MB)
#define PART_OFF 16384
#define W1T_OFF  (1024 * 1024)
#define WS_NEED  (W1T_OFF + 8 * 1024 * 1024)

__device__ __forceinline__ unsigned short f2bf(float f) {
    union { float f; unsigned int u; } v; v.f = f;
    unsigned int u = v.u;
    return (unsigned short)((u + 0x7fffu + ((u >> 16) & 1u)) >> 16);
}

// ---- prep: blocks 0..1023 transpose W1 -> w1t bf16 [T][H][D]; block 1024 sorts ----
__global__ __launch_bounds__(256) void nk_prep(const float* __restrict__ W1,
                                               const int* __restrict__ task_id,
                                               unsigned short* __restrict__ w1t,
                                               int* __restrict__ wsi) {
    int bid = blockIdx.x;
    int tid = threadIdx.x;
    if (bid < 1024) {
        __shared__ float tile[64][65];
        int hx = bid & 7, dy = (bid >> 3) & 7, t = bid >> 6;
        int cx = tid & 63, ry = tid >> 6;
        const float* src = W1 + ((size_t)t * D_ + dy * 64) * H_ + hx * 64;
#pragma unroll
        for (int i = 0; i < 16; ++i) {
            int row = i * 4 + ry;
            tile[row][cx] = src[(size_t)row * H_ + cx];
        }
        __syncthreads();
        unsigned short* dst = w1t + ((size_t)t * H_ + hx * 64) * D_ + dy * 64;
#pragma unroll
        for (int i = 0; i < 16; ++i) {
            int hr = i * 4 + ry;
            dst[(size_t)hr * D_ + cx] = f2bf(tile[cx][hr]);
        }
    } else {
        // sort block
        __shared__ int cnt[T_], cur[T_], soff[T_];
        if (tid < T_) { cnt[tid] = 0; cur[tid] = 0; }
        __syncthreads();
        for (int b = tid; b < B_; b += 256) atomicAdd(&cnt[task_id[b]], 1);
        __syncthreads();
        if (tid == 0) {
            int off = 0, tot = 0;
            for (int t = 0; t < T_; ++t) {
                soff[t] = off; wsi[17 + t] = off;
                int nt = (cnt[t] + MT - 1) / MT;
                for (int k = 0; k < nt; ++k) wsi[50 + tot++] = (t << 16) | k;
                off += cnt[t];
            }
            wsi[17 + T_] = off;
            wsi[0] = tot;
        }
        __syncthreads();
        for (int b = tid; b < B_; b += 256) {
            int t = task_id[b];
            int pos = atomicAdd(&cur[t], 1);
            wsi[256 + soff[t] + pos] = b;
        }
    }
}

// ---- gemm1 + relu + partial fc2 (per 128-col quarter) ----
__global__ __launch_bounds__(256) void nk_gemm(const float* __restrict__ xs,
                                               const unsigned short* __restrict__ w1t,
                                               const float* __restrict__ b1,
                                               const float* __restrict__ W2,
                                               float* __restrict__ part,
                                               const int* __restrict__ wsi) {
    __shared__ int sidx[MT];
    __shared__ float h_lds[MT][132];      // 16 x 132 fp32 = 8.4 KB

    int tile = blockIdx.x;
    if (tile >= wsi[0]) return;
    int code = wsi[50 + tile];
    int t = code >> 16, kt = code & 0xffff;
    int off0 = wsi[17 + t], off1 = wsi[17 + t + 1];
    int rowbase = off0 + kt * MT;
    int rows = off1 - rowbase; if (rows > MT) rows = MT;

    int tid = threadIdx.x, lane = tid & 63, w = tid >> 6;
    int r15 = lane & 15, kg = lane >> 4;
    int cq = blockIdx.y;

    if (tid < MT) sidx[tid] = wsi[256 + rowbase + (tid < rows ? tid : rows - 1)];
    __syncthreads();

    // fc1: wave w covers cols cq*128 + w*32 .. +32 (2 n-tiles), 16 rows
    int arow = sidx[r15];
    const float* ap = xs + (size_t)arow * D_ + kg * 8;
    int col0 = cq * 128 + w * 32;
    const unsigned short* bp0 = w1t + (size_t)t * H_ * D_ + (size_t)(col0 + r15) * D_ + kg * 8;
    const unsigned short* bp1 = bp0 + (size_t)16 * D_;

    f32x4 acc0 = {0.f, 0.f, 0.f, 0.f}, acc1 = {0.f, 0.f, 0.f, 0.f};
#pragma unroll
    for (int ks = 0; ks < 16; ++ks) {
        float4 x0 = *(const float4*)(ap + ks * 32);
        float4 x1 = *(const float4*)(ap + ks * 32 + 4);
        unsigned short u[8] = { f2bf(x0.x), f2bf(x0.y), f2bf(x0.z), f2bf(x0.w),
                                f2bf(x1.x), f2bf(x1.y), f2bf(x1.z), f2bf(x1.w) };
        short8 afrag = *(const short8*)u;
        short8 bf0 = *(const short8*)(bp0 + ks * 32);
        short8 bf1 = *(const short8*)(bp1 + ks * 32);
        acc0 = __builtin_amdgcn_mfma_f32_16x16x32_bf16(afrag, bf0, acc0, 0, 0, 0);
        acc1 = __builtin_amdgcn_mfma_f32_16x16x32_bf16(afrag, bf1, acc1, 0, 0, 0);
    }

    // bias + relu -> h_lds (local cols w*32 + r15 (+16))
    float bv0 = b1[t * H_ + col0 + r15];
    float bv1 = b1[t * H_ + col0 + 16 + r15];
#pragma unroll
    for (int j = 0; j < 4; ++j) {
        int rr = kg * 4 + j;
        float v0 = acc0[j] + bv0;
        float v1 = acc1[j] + bv1;
        h_lds[rr][w * 32 + r15] = v0 > 0.f ? v0 : 0.f;
        h_lds[rr][w * 32 + 16 + r15] = v1 > 0.f ? v1 : 0.f;
    }
    __syncthreads();

    // partial fc2 over this block's 128 h-cols: 16 lanes per row
    int g = tid >> 4, l16 = tid & 15;
    float lg[A_];
#pragma unroll
    for (int a = 0; a < A_; ++a) lg[a] = 0.f;
    float4 hv0 = *(const float4*)&h_lds[g][l16 * 8];
    float4 hv1 = *(const float4*)&h_lds[g][l16 * 8 + 4];
    const float* wr = W2 + ((size_t)t * H_ + cq * 128 + l16 * 8) * A_;
#pragma unroll
    for (int a = 0; a < A_; ++a) {
        float s = fmaf(hv0.x, wr[a], lg[a]);
        s = fmaf(hv0.y, wr[A_ + a], s);
        s = fmaf(hv0.z, wr[2 * A_ + a], s);
        s = fmaf(hv0.w, wr[3 * A_ + a], s);
        s = fmaf(hv1.x, wr[4 * A_ + a], s);
        s = fmaf(hv1.y, wr[5 * A_ + a], s);
        s = fmaf(hv1.z, wr[6 * A_ + a], s);
        lg[a] = fmaf(hv1.w, wr[7 * A_ + a], s);
    }
#pragma unroll
    for (int a = 0; a < A_; ++a) {
        lg[a] += __shfl_down(lg[a], 8, 16);
        lg[a] += __shfl_down(lg[a], 4, 16);
        lg[a] += __shfl_down(lg[a], 2, 16);
        lg[a] += __shfl_down(lg[a], 1, 16);
    }
    if (l16 == 0 && g < rows) {
        float* pp = part + ((size_t)cq * B_ + rowbase + g) * A_;
#pragma unroll
        for (int a = 0; a < A_; ++a) pp[a] = lg[a];
    }
}

// ---- final: sum 4 partials + bias, softmax, write outputs ----
__global__ __launch_bounds__(256) void nk_final(const float* __restrict__ part,
                                                const float* __restrict__ b2,
                                                const int* __restrict__ action,
                                                float* __restrict__ out,
                                                const int* __restrict__ wsi) {
    int r = blockIdx.x * 256 + threadIdx.x;   // sorted row
    if (r >= B_) return;
    int t = 0;
#pragma unroll
    for (int i = 1; i < T_; ++i) t += (r >= wsi[17 + i]) ? 1 : 0;
    int b = wsi[256 + r];

    const float* p0 = part + (size_t)r * A_;
    float logits[A_];
    float m = -1e30f;
#pragma unroll
    for (int a = 0; a < A_; ++a) {
        float v = p0[a] + p0[(size_t)B_ * A_ + a] + p0[2 * (size_t)B_ * A_ + a]
                + p0[3 * (size_t)B_ * A_ + a] + b2[t * A_ + a];
        logits[a] = v;
        m = fmaxf(m, v);
    }
    float S = 0.f, sle = 0.f;
#pragma unroll
    for (int a = 0; a < A_; ++a) {
        float e = expf(logits[a] - m);
        S += e;
        sle += logits[a] * e;
    }
    float logZ = m + logf(S);
    int as = action[b];
    out[b] = (float)as;
    out[B_ + b] = logits[as] - logZ;
    out[2 * B_ + b] = logZ - sle / S;
}

// ---------------- fallback path (round-1, known-good) ----------------

__global__ void nk_init(int* wsi) { int i = threadIdx.x; if (i < 50) wsi[i] = 0; }

__global__ void nk_count(const int* task_id, int* wsi) {
    int b = blockIdx.x * blockDim.x + threadIdx.x;
    if (b < B_) atomicAdd(&wsi[1 + task_id[b]], 1);
}

__global__ void nk_plan(int* wsi) {
    int off = 0, tot = 0;
    for (int t = 0; t < T_; ++t) {
        wsi[17 + t] = off;
        int cnt = wsi[1 + t];
        int nt = (cnt + MT - 1) / MT;
        for (int k = 0; k < nt; ++k) wsi[50 + tot++] = (t << 16) | k;
        off += cnt;
    }
    wsi[17 + T_] = off;
    wsi[0] = tot;
}

__global__ void nk_scatter(const int* task_id, int* wsi) {
    int b = blockIdx.x * blockDim.x + threadIdx.x;
    if (b < B_) {
        int t = task_id[b];
        int pos = atomicAdd(&wsi[34 + t], 1);
        wsi[256 + wsi[17 + t] + pos] = b;
    }
}

__global__ __launch_bounds__(512) void nk_main(
        const float* __restrict__ xs, const float* __restrict__ W1,
        const float* __restrict__ b1, const float* __restrict__ W2,
        const float* __restrict__ b2, const int* __restrict__ task_id,
        const int* __restrict__ action, float* __restrict__ out,
        const int* __restrict__ wsi) {
    __shared__ float tile[MT][D_];
    __shared__ int sidx[MT];
    int bid = blockIdx.x;
    if (bid >= wsi[0]) return;
    int code = wsi[50 + bid];
    int t = code >> 16, kt = code & 0xffff;
    int off0 = wsi[17 + t], off1 = wsi[17 + t + 1];
    int base = off0 + kt * MT;
    int rows = off1 - base; if (rows > MT) rows = MT;
    int tid = threadIdx.x;
    if (tid < MT) sidx[tid] = (tid < rows) ? wsi[256 + base + tid] : -1;
    __syncthreads();
    for (int i = 0; i < MT; ++i) {
        int b = sidx[i];
        tile[i][tid] = (b >= 0) ? xs[(size_t)b * D_ + tid] : 0.f;
    }
    __syncthreads();
    const float* w1p = W1 + (size_t)t * D_ * H_ + tid;
    float acc[MT];
#pragma unroll
    for (int i = 0; i < MT; ++i) acc[i] = 0.f;
    for (int d = 0; d < D_; d += 4) {
        float w0 = w1p[(size_t)(d + 0) * H_];
        float w1v = w1p[(size_t)(d + 1) * H_];
        float w2v = w1p[(size_t)(d + 2) * H_];
        float w3v = w1p[(size_t)(d + 3) * H_];
#pragma unroll
        for (int i = 0; i < MT; ++i) {
            float4 x = *(const float4*)&tile[i][d];
            float a0 = fmaf(x.x, w0, acc[i]);
            a0 = fmaf(x.y, w1v, a0);
            a0 = fmaf(x.z, w2v, a0);
            acc[i] = fmaf(x.w, w3v, a0);
        }
    }
    __syncthreads();
    float b1v = b1[t * H_ + tid];
#pragma unroll
    for (int i = 0; i < MT; ++i) {
        float h = acc[i] + b1v;
        tile[i][tid] = h > 0.f ? h : 0.f;
    }
    __syncthreads();
    int g = tid >> 5, l = tid & 31;
    float lg[A_];
#pragma unroll
    for (int a = 0; a < A_; ++a) lg[a] = 0.f;
    const float* w2base = W2 + (size_t)t * H_ * A_;
    for (int hh = l; hh < H_; hh += 32) {
        float hv = tile[g][hh];
        const float* wrow = w2base + (size_t)hh * A_;
#pragma unroll
        for (int a = 0; a < A_; ++a) lg[a] = fmaf(hv, wrow[a], lg[a]);
    }
#pragma unroll
    for (int a = 0; a < A_; ++a) {
        lg[a] += __shfl_down(lg[a], 16, 32);
        lg[a] += __shfl_down(lg[a], 8, 32);
        lg[a] += __shfl_down(lg[a], 4, 32);
        lg[a] += __shfl_down(lg[a], 2, 32);
        lg[a] += __shfl_down(lg[a], 1, 32);
    }
    if (l == 0 && g < rows) {
        int b = sidx[g];
        float logits[A_];
        float m = -1e30f;
#pragma unroll
        for (int a = 0; a < A_; ++a) {
            logits[a] = lg[a] + b2[t * A_ + a];
            m = fmaxf(m, logits[a]);
        }
        float S = 0.f, sle = 0.f;
#pragma unroll
        for (int a = 0; a < A_; ++a) {
            float e = expf(logits[a] - m);
            S += e;
            sle += logits[a] * e;
        }
        float logZ = m + logf(S);
        int as = action[b];
        out[b] = (float)as;
        out[B_ + b] = logits[as] - logZ;
        out[2 * B_ + b] = logZ - sle / S;
    }
}

extern "C" void kernel_launch(void* const* d_in, const int* in_sizes, int n_in,
                              void* d_out, int out_size, void* d_ws, size_t ws_size,
                              hipStream_t stream) {
    const float* xs = (const float*)d_in[0];
    const float* W1 = (const float*)d_in[1];
    const float* b1 = (const float*)d_in[2];
    const float* W2 = (const float*)d_in[3];
    const float* b2 = (const float*)d_in[4];
    const int* task_id = (const int*)d_in[5];
    const int* action = (const int*)d_in[6];
    float* out = (float*)d_out;

    if (ws_size >= WS_NEED) {
        unsigned char* wsb = (unsigned char*)d_ws;
        int* wsi = (int*)d_ws;
        float* part = (float*)(wsb + PART_OFF);
        unsigned short* w1t = (unsigned short*)(wsb + W1T_OFF);

        nk_prep<<<1025, 256, 0, stream>>>(W1, task_id, w1t, wsi);
        nk_gemm<<<dim3(MAXTILES, 4), 256, 0, stream>>>(xs, w1t, b1, W2, part, wsi);
        nk_final<<<(B_ + 255) / 256, 256, 0, stream>>>(part, b2, action, out, wsi);
    } else {
        int* wsi = (int*)d_ws;
        nk_init<<<1, 64, 0, stream>>>(wsi);
        nk_count<<<(B_ + 255) / 256, 256, 0, stream>>>(task_id, wsi);
        nk_plan<<<1, 1, 0, stream>>>(wsi);
        nk_scatter<<<(B_ + 255) / 256, 256, 0, stream>>>(task_id, wsi);
        nk_main<<<MAXTILES, 512, 0, stream>>>(xs, W1, b1, W2, b2, task_id, action, out, wsi);
    }
}

// Round 5
// 46.107 us; speedup vs baseline: 1.6710x; 1.1028x over previous
//
#include <hip/hip_runtime.h>
#include <math.h>

#define B_ 2048
#define D_ 512
#define H_ 512
#define A_ 18
#define T_ 16
#define MT 32
#define MAXTILES 80     // B/32 + T
#define MTF 16
#define MAXTILESF 144

typedef __attribute__((ext_vector_type(8))) short short8;
typedef __attribute__((ext_vector_type(4))) float f32x4;

// ws layout:
//   [0..16384)   ints: [0] ntiles | [17..34) offsets[T+1] | [50..130) tiles | [256..2304) order[B]
//   PART_OFF     float part[4][B][A]   (576 KB)
//   XSB_OFF      bf16 xs_b[B][D]       (2 MB)
//   W1T_OFF      bf16 w1t[T][H][D]     (8 MB)
#define PART_OFF 16384
#define XSB_OFF  (1 << 20)
#define W1T_OFF  (4 << 20)
#define WS_NEED  (12 << 20)

__device__ __forceinline__ unsigned short f2bf(float f) {
    union { float f; unsigned int u; } v; v.f = f;
    unsigned int u = v.u;
    return (unsigned short)((u + 0x7fffu + ((u >> 16) & 1u)) >> 16);
}

// ---- prep: [0,1024) W1 transpose->bf16; [1024,1536) xs->bf16; 1536 sort ----
__global__ __launch_bounds__(256) void nk_prep(const float* __restrict__ W1,
                                               const float* __restrict__ xs,
                                               const int* __restrict__ task_id,
                                               unsigned short* __restrict__ w1t,
                                               unsigned short* __restrict__ xs_b,
                                               int* __restrict__ wsi) {
    int bid = blockIdx.x;
    int tid = threadIdx.x;
    if (bid < 1024) {
        __shared__ float tile[64][65];
        int hx = bid & 7, dy = (bid >> 3) & 7, t = bid >> 6;
        int cx = tid & 63, ry = tid >> 6;
        const float* src = W1 + ((size_t)t * D_ + dy * 64) * H_ + hx * 64;
#pragma unroll
        for (int i = 0; i < 16; ++i) {
            int row = i * 4 + ry;
            tile[row][cx] = src[(size_t)row * H_ + cx];
        }
        __syncthreads();
        // vectorized store: thread -> (hr, 4 consecutive d), uint2 = 4 bf16
        unsigned short* dst = w1t + ((size_t)t * H_ + hx * 64) * D_ + dy * 64;
        int c4 = tid & 15, hr0 = tid >> 4;
#pragma unroll
        for (int i = 0; i < 4; ++i) {
            int hr = hr0 + i * 16;
            unsigned short u[4] = { f2bf(tile[c4 * 4 + 0][hr]), f2bf(tile[c4 * 4 + 1][hr]),
                                    f2bf(tile[c4 * 4 + 2][hr]), f2bf(tile[c4 * 4 + 3][hr]) };
            *(uint2*)(dst + (size_t)hr * D_ + c4 * 4) = *(const uint2*)u;
        }
    } else if (bid < 1536) {
        size_t off = ((size_t)(bid - 1024) * 256 + tid) * 8;
        float4 x0 = *(const float4*)(xs + off);
        float4 x1 = *(const float4*)(xs + off + 4);
        unsigned short u[8] = { f2bf(x0.x), f2bf(x0.y), f2bf(x0.z), f2bf(x0.w),
                                f2bf(x1.x), f2bf(x1.y), f2bf(x1.z), f2bf(x1.w) };
        *(uint4*)(xs_b + off) = *(const uint4*)u;
    } else {
        __shared__ int cnt[T_], cur[T_], soff[T_];
        if (tid < T_) { cnt[tid] = 0; cur[tid] = 0; }
        __syncthreads();
        for (int b = tid; b < B_; b += 256) atomicAdd(&cnt[task_id[b]], 1);
        __syncthreads();
        if (tid == 0) {
            int off = 0, tot = 0;
            for (int t = 0; t < T_; ++t) {
                soff[t] = off; wsi[17 + t] = off;
                int nt = (cnt[t] + MT - 1) / MT;
                for (int k = 0; k < nt; ++k) wsi[50 + tot++] = (t << 16) | k;
                off += cnt[t];
            }
            wsi[17 + T_] = off;
            wsi[0] = tot;
        }
        __syncthreads();
        for (int b = tid; b < B_; b += 256) {
            int t = task_id[b];
            int pos = atomicAdd(&cur[t], 1);
            wsi[256 + soff[t] + pos] = b;
        }
    }
}

// ---- gemm1 (32 rows x 128 cols per block) + relu + partial fc2 ----
__global__ __launch_bounds__(256) void nk_gemm(const unsigned short* __restrict__ xs_b,
                                               const unsigned short* __restrict__ w1t,
                                               const float* __restrict__ b1,
                                               const float* __restrict__ W2,
                                               float* __restrict__ part,
                                               const int* __restrict__ wsi) {
    __shared__ int sidx[MT];
    __shared__ float h_lds[MT][132];      // 32 x 132 fp32 = 16.9 KB

    int tile = blockIdx.x;
    if (tile >= wsi[0]) return;
    int code = wsi[50 + tile];
    int t = code >> 16, kt = code & 0xffff;
    int off0 = wsi[17 + t], off1 = wsi[17 + t + 1];
    int rowbase = off0 + kt * MT;
    int rows = off1 - rowbase; if (rows > MT) rows = MT;

    int tid = threadIdx.x, lane = tid & 63, w = tid >> 6;
    int r15 = lane & 15, kg = lane >> 4;
    int cq = blockIdx.y;

    if (tid < MT) sidx[tid] = wsi[256 + rowbase + (tid < rows ? tid : rows - 1)];
    __syncthreads();

    const unsigned short* ap0 = xs_b + (size_t)sidx[r15] * D_ + kg * 8;
    const unsigned short* ap1 = xs_b + (size_t)sidx[16 + r15] * D_ + kg * 8;
    int col0 = cq * 128 + w * 32;
    const unsigned short* bp0 = w1t + (size_t)t * H_ * D_ + (size_t)(col0 + r15) * D_ + kg * 8;
    const unsigned short* bp1 = bp0 + (size_t)16 * D_;

    f32x4 acc00 = {0.f,0.f,0.f,0.f}, acc01 = {0.f,0.f,0.f,0.f};
    f32x4 acc10 = {0.f,0.f,0.f,0.f}, acc11 = {0.f,0.f,0.f,0.f};
#pragma unroll
    for (int ks = 0; ks < 16; ++ks) {
        short8 a0 = *(const short8*)(ap0 + ks * 32);
        short8 a1 = *(const short8*)(ap1 + ks * 32);
        short8 bf0 = *(const short8*)(bp0 + ks * 32);
        short8 bf1 = *(const short8*)(bp1 + ks * 32);
        acc00 = __builtin_amdgcn_mfma_f32_16x16x32_bf16(a0, bf0, acc00, 0, 0, 0);
        acc01 = __builtin_amdgcn_mfma_f32_16x16x32_bf16(a0, bf1, acc01, 0, 0, 0);
        acc10 = __builtin_amdgcn_mfma_f32_16x16x32_bf16(a1, bf0, acc10, 0, 0, 0);
        acc11 = __builtin_amdgcn_mfma_f32_16x16x32_bf16(a1, bf1, acc11, 0, 0, 0);
    }

    float bv0 = b1[t * H_ + col0 + r15];
    float bv1 = b1[t * H_ + col0 + 16 + r15];
#pragma unroll
    for (int j = 0; j < 4; ++j) {
        int rr = kg * 4 + j;
        float v;
        v = acc00[j] + bv0; h_lds[rr][w * 32 + r15]           = v > 0.f ? v : 0.f;
        v = acc01[j] + bv1; h_lds[rr][w * 32 + 16 + r15]      = v > 0.f ? v : 0.f;
        v = acc10[j] + bv0; h_lds[16 + rr][w * 32 + r15]      = v > 0.f ? v : 0.f;
        v = acc11[j] + bv1; h_lds[16 + rr][w * 32 + 16 + r15] = v > 0.f ? v : 0.f;
    }
    __syncthreads();

    // partial fc2 over this block's 128 h-cols: 16 lanes/row, 2 row-groups
    int gb = tid >> 4, l16 = tid & 15;
    const float* wr = W2 + ((size_t)t * H_ + cq * 128 + l16 * 8) * A_;
#pragma unroll
    for (int gg = 0; gg < 2; ++gg) {
        int g = gb + gg * 16;
        float lg[A_];
#pragma unroll
        for (int a = 0; a < A_; ++a) lg[a] = 0.f;
        float4 hv0 = *(const float4*)&h_lds[g][l16 * 8];
        float4 hv1 = *(const float4*)&h_lds[g][l16 * 8 + 4];
#pragma unroll
        for (int a = 0; a < A_; ++a) {
            float s = fmaf(hv0.x, wr[a], lg[a]);
            s = fmaf(hv0.y, wr[A_ + a], s);
            s = fmaf(hv0.z, wr[2 * A_ + a], s);
            s = fmaf(hv0.w, wr[3 * A_ + a], s);
            s = fmaf(hv1.x, wr[4 * A_ + a], s);
            s = fmaf(hv1.y, wr[5 * A_ + a], s);
            s = fmaf(hv1.z, wr[6 * A_ + a], s);
            lg[a] = fmaf(hv1.w, wr[7 * A_ + a], s);
        }
#pragma unroll
        for (int a = 0; a < A_; ++a) {
            lg[a] += __shfl_down(lg[a], 8, 16);
            lg[a] += __shfl_down(lg[a], 4, 16);
            lg[a] += __shfl_down(lg[a], 2, 16);
            lg[a] += __shfl_down(lg[a], 1, 16);
        }
        if (l16 == 0 && g < rows) {
            float* pp = part + ((size_t)cq * B_ + rowbase + g) * A_;
#pragma unroll
            for (int a = 0; a < A_; ++a) pp[a] = lg[a];
        }
    }
}

// ---- final: sum 4 partials + bias, softmax, write outputs ----
__global__ __launch_bounds__(256) void nk_final(const float* __restrict__ part,
                                                const float* __restrict__ b2,
                                                const int* __restrict__ action,
                                                float* __restrict__ out,
                                                const int* __restrict__ wsi) {
    int r = blockIdx.x * 256 + threadIdx.x;
    if (r >= B_) return;
    int t = 0;
#pragma unroll
    for (int i = 1; i < T_; ++i) t += (r >= wsi[17 + i]) ? 1 : 0;
    int b = wsi[256 + r];

    const float* p0 = part + (size_t)r * A_;
    float logits[A_];
    float m = -1e30f;
#pragma unroll
    for (int a = 0; a < A_; ++a) {
        float v = p0[a] + p0[(size_t)B_ * A_ + a] + p0[2 * (size_t)B_ * A_ + a]
                + p0[3 * (size_t)B_ * A_ + a] + b2[t * A_ + a];
        logits[a] = v;
        m = fmaxf(m, v);
    }
    float S = 0.f, sle = 0.f;
#pragma unroll
    for (int a = 0; a < A_; ++a) {
        float e = expf(logits[a] - m);
        S += e;
        sle += logits[a] * e;
    }
    float logZ = m + logf(S);
    int as = action[b];
    out[b] = (float)as;
    out[B_ + b] = logits[as] - logZ;
    out[2 * B_ + b] = logZ - sle / S;
}

// ---------------- fallback path (round-1, known-good) ----------------

__global__ void nk_init(int* wsi) { int i = threadIdx.x; if (i < 50) wsi[i] = 0; }

__global__ void nk_count(const int* task_id, int* wsi) {
    int b = blockIdx.x * blockDim.x + threadIdx.x;
    if (b < B_) atomicAdd(&wsi[1 + task_id[b]], 1);
}

__global__ void nk_plan(int* wsi) {
    int off = 0, tot = 0;
    for (int t = 0; t < T_; ++t) {
        wsi[17 + t] = off;
        int cnt = wsi[1 + t];
        int nt = (cnt + MTF - 1) / MTF;
        for (int k = 0; k < nt; ++k) wsi[50 + tot++] = (t << 16) | k;
        off += cnt;
    }
    wsi[17 + T_] = off;
    wsi[0] = tot;
}

__global__ void nk_scatter(const int* task_id, int* wsi) {
    int b = blockIdx.x * blockDim.x + threadIdx.x;
    if (b < B_) {
        int t = task_id[b];
        int pos = atomicAdd(&wsi[34 + t], 1);
        wsi[256 + wsi[17 + t] + pos] = b;
    }
}

__global__ __launch_bounds__(512) void nk_main(
        const float* __restrict__ xs, const float* __restrict__ W1,
        const float* __restrict__ b1, const float* __restrict__ W2,
        const float* __restrict__ b2, const int* __restrict__ task_id,
        const int* __restrict__ action, float* __restrict__ out,
        const int* __restrict__ wsi) {
    __shared__ float tile[MTF][D_];
    __shared__ int sidx[MTF];
    int bid = blockIdx.x;
    if (bid >= wsi[0]) return;
    int code = wsi[50 + bid];
    int t = code >> 16, kt = code & 0xffff;
    int off0 = wsi[17 + t], off1 = wsi[17 + t + 1];
    int base = off0 + kt * MTF;
    int rows = off1 - base; if (rows > MTF) rows = MTF;
    int tid = threadIdx.x;
    if (tid < MTF) sidx[tid] = (tid < rows) ? wsi[256 + base + tid] : -1;
    __syncthreads();
    for (int i = 0; i < MTF; ++i) {
        int b = sidx[i];
        tile[i][tid] = (b >= 0) ? xs[(size_t)b * D_ + tid] : 0.f;
    }
    __syncthreads();
    const float* w1p = W1 + (size_t)t * D_ * H_ + tid;
    float acc[MTF];
#pragma unroll
    for (int i = 0; i < MTF; ++i) acc[i] = 0.f;
    for (int d = 0; d < D_; d += 4) {
        float w0 = w1p[(size_t)(d + 0) * H_];
        float w1v = w1p[(size_t)(d + 1) * H_];
        float w2v = w1p[(size_t)(d + 2) * H_];
        float w3v = w1p[(size_t)(d + 3) * H_];
#pragma unroll
        for (int i = 0; i < MTF; ++i) {
            float4 x = *(const float4*)&tile[i][d];
            float a0 = fmaf(x.x, w0, acc[i]);
            a0 = fmaf(x.y, w1v, a0);
            a0 = fmaf(x.z, w2v, a0);
            acc[i] = fmaf(x.w, w3v, a0);
        }
    }
    __syncthreads();
    float b1v = b1[t * H_ + tid];
#pragma unroll
    for (int i = 0; i < MTF; ++i) {
        float h = acc[i] + b1v;
        tile[i][tid] = h > 0.f ? h : 0.f;
    }
    __syncthreads();
    int g = tid >> 5, l = tid & 31;
    float lg[A_];
#pragma unroll
    for (int a = 0; a < A_; ++a) lg[a] = 0.f;
    const float* w2base = W2 + (size_t)t * H_ * A_;
    for (int hh = l; hh < H_; hh += 32) {
        float hv = tile[g][hh];
        const float* wrow = w2base + (size_t)hh * A_;
#pragma unroll
        for (int a = 0; a < A_; ++a) lg[a] = fmaf(hv, wrow[a], lg[a]);
    }
#pragma unroll
    for (int a = 0; a < A_; ++a) {
        lg[a] += __shfl_down(lg[a], 16, 32);
        lg[a] += __shfl_down(lg[a], 8, 32);
        lg[a] += __shfl_down(lg[a], 4, 32);
        lg[a] += __shfl_down(lg[a], 2, 32);
        lg[a] += __shfl_down(lg[a], 1, 32);
    }
    if (l == 0 && g < rows) {
        int b = sidx[g];
        float logits[A_];
        float m = -1e30f;
#pragma unroll
        for (int a = 0; a < A_; ++a) {
            logits[a] = lg[a] + b2[t * A_ + a];
            m = fmaxf(m, logits[a]);
        }
        float S = 0.f, sle = 0.f;
#pragma unroll
        for (int a = 0; a < A_; ++a) {
            float e = expf(logits[a] - m);
            S += e;
            sle += logits[a] * e;
        }
        float logZ = m + logf(S);
        int as = action[b];
        out[b] = (float)as;
        out[B_ + b] = logits[as] - logZ;
        out[2 * B_ + b] = logZ - sle / S;
    }
}

extern "C" void kernel_launch(void* const* d_in, const int* in_sizes, int n_in,
                              void* d_out, int out_size, void* d_ws, size_t ws_size,
                              hipStream_t stream) {
    const float* xs = (const float*)d_in[0];
    const float* W1 = (const float*)d_in[1];
    const float* b1 = (const float*)d_in[2];
    const float* W2 = (const float*)d_in[3];
    const float* b2 = (const float*)d_in[4];
    const int* task_id = (const int*)d_in[5];
    const int* action = (const int*)d_in[6];
    float* out = (float*)d_out;

    if (ws_size >= WS_NEED) {
        unsigned char* wsb = (unsigned char*)d_ws;
        int* wsi = (int*)d_ws;
        float* part = (float*)(wsb + PART_OFF);
        unsigned short* xs_b = (unsigned short*)(wsb + XSB_OFF);
        unsigned short* w1t = (unsigned short*)(wsb + W1T_OFF);

        nk_prep<<<1537, 256, 0, stream>>>(W1, xs, task_id, w1t, xs_b, wsi);
        nk_gemm<<<dim3(MAXTILES, 4), 256, 0, stream>>>(xs_b, w1t, b1, W2, part, wsi);
        nk_final<<<(B_ + 255) / 256, 256, 0, stream>>>(part, b2, action, out, wsi);
    } else {
        int* wsi = (int*)d_ws;
        nk_init<<<1, 64, 0, stream>>>(wsi);
        nk_count<<<(B_ + 255) / 256, 256, 0, stream>>>(task_id, wsi);
        nk_plan<<<1, 1, 0, stream>>>(wsi);
        nk_scatter<<<(B_ + 255) / 256, 256, 0, stream>>>(task_id, wsi);
        nk_main<<<MAXTILESF, 512, 0, stream>>>(xs, W1, b1, W2, b2, task_id, action, out, wsi);
    }
}